// Round 1
// 246.415 us; speedup vs baseline: 1.1419x; 1.1419x over previous
//
#include <hip/hip_runtime.h>
#include <hip/hip_bf16.h>

#define DIMD 768
#define RNK  48
#define KADP 4
#define NB   8
#define NS   4096
#define NKR  192
#define GSTR 200          // g region row stride (bf16 elems)
#define XSTR 392          // x_lds row stride (bf16 elems): 384 data + 8 pad; 784B rows

typedef __attribute__((ext_vector_type(8))) short short8;
typedef __attribute__((ext_vector_type(4))) short short4v;
typedef __attribute__((ext_vector_type(4))) float floatx4;

__device__ __forceinline__ short f2bf(float f) {
    union { float f; unsigned u; } v; v.f = f;
    unsigned u = v.u;
    unsigned r = (u + 0x7fffu + ((u >> 16) & 1u)) >> 16;   // RNE
    return (short)(r & 0xffffu);
}

// ---------------------------------------------------------------------------
// Prologue: blocks 0..1023 = pool partial sums (32 s-rows each, 12 waves/CU
// for latency hiding vs old 256-block/1-per-CU version); blocks 1024..1167 =
// weight pack. pool must be zeroed by hipMemsetAsync before this kernel.
// Wd raw [k,d,r] -> down-B-frag: B[k=d][n=kr], kr=k*48+r
// Wu raw [k,r,d] -> up-B-frag:   B[k=kr][n=d]
// Packed addr (bf16): ((nt*KC + kc)*64 + lane)*8 + j ; k-in-chunk = quad*8+j
// ---------------------------------------------------------------------------
__global__ void prologue(const float* __restrict__ x,
                         const float* __restrict__ Wd, const float* __restrict__ Wu,
                         short* __restrict__ WdP, short* __restrict__ WuP,
                         float* __restrict__ pool) {
    int blk = blockIdx.x;
    int tid = threadIdx.x;
    if (blk < 1024) {                     // ---- pool partial ----
        if (tid >= 192) return;
        int b = blk >> 7, sc = blk & 127; // 32 s per block
        int d4 = tid * 4;
        const float* xp = x + ((size_t)(b * NS + sc * 32)) * DIMD + d4;
        float4 acc = {0.f, 0.f, 0.f, 0.f};
#pragma unroll 8
        for (int s = 0; s < 32; ++s) {
            float4 v = *(const float4*)(xp + (size_t)s * DIMD);
            acc.x += v.x; acc.y += v.y; acc.z += v.z; acc.w += v.w;
        }
        atomicAdd(&pool[b * DIMD + d4 + 0], acc.x);
        atomicAdd(&pool[b * DIMD + d4 + 1], acc.y);
        atomicAdd(&pool[b * DIMD + d4 + 2], acc.z);
        atomicAdd(&pool[b * DIMD + d4 + 3], acc.w);
        return;
    }
    int i = (blk - 1024) * 256 + tid;     // ---- weight pack ----
    if (i < 18432) {                      // Wd: 12 nt * 24 kc * 64 lanes
        int lane = i & 63, tile = i >> 6;
        int kc = tile % 24, nt = tile / 24;
        int col = lane & 15, quad = lane >> 4;
        int kr = nt * 16 + col;
        int k = kr / RNK, r = kr % RNK;
        short8 vals;
#pragma unroll
        for (int j = 0; j < 8; ++j) {
            int d = kc * 32 + quad * 8 + j;
            vals[j] = f2bf(Wd[(k * DIMD + d) * RNK + r]);
        }
        *(short8*)(WdP + (size_t)i * 8) = vals;
    } else if (i < 36864) {               // Wu: 48 nt * 6 kc * 64 lanes
        int i2 = i - 18432;
        int lane = i2 & 63, tile = i2 >> 6;
        int kc = tile % 6, nt = tile / 6;
        int col = lane & 15, quad = lane >> 4;
        int d = nt * 16 + col;
        short8 vals;
#pragma unroll
        for (int j = 0; j < 8; ++j) {
            int krk = kc * 32 + quad * 8 + j;
            int k = krk / RNK, r = krk % RNK;
            vals[j] = f2bf(Wu[(k * RNK + r) * DIMD + d]);
        }
        *(short8*)(WuP + (size_t)i2 * 8) = vals;
    }
}

// ---------------------------------------------------------------------------
// Main: grid(128,8), block 256 = 4 waves. Block owns 32 tokens (2 m-tiles).
// Occupancy redesign vs previous version:
//   - x tile staged in TWO k-halves (32 x 384 bf16, stride 392) -> LDS 25.1KB
//     -> 6 blocks/CU (was 49.7KB -> 3/CU), m-reuse=2 preserved.
//   - phase 2 split into two m-tile passes so ga[] is 24 VGPR not 48;
//     __launch_bounds__(256,8) caps VGPR at 64 (occupancy steps at 64/128).
//   - router folded in: each block computes w[b,:] from pool (shuffle reduce,
//     softmax redundant per thread) and folds sum_k w_k*bu[k,d] into the
//     phase-2 epilogue. No router kernel, no biasb/w_vec buffers.
//   - out stores nontemporal: keep x resident in L3 for other blocks.
// MFMA 16x16x32 bf16 layouts (HW-verified):
//   A: lane holds A[m=lane&15][k=quad*8+j] ; B: B[k=quad*8+j][n=lane&15]
//   C: lane holds C[row=quad*4+reg][col=lane&15]
// ---------------------------------------------------------------------------
__launch_bounds__(256, 8)
__global__ void adapter_main(const float* __restrict__ x,
                             const float* __restrict__ bd,
                             const short* __restrict__ WdP,
                             const short* __restrict__ WuP,
                             const float* __restrict__ pool,
                             const float* __restrict__ Wr,
                             const float* __restrict__ br,
                             const float* __restrict__ bu,
                             float* __restrict__ out) {
    __shared__ short smem[32 * XSTR];          // 25088 B; g region aliases front
    __shared__ float wsh[16];                  // [wave][k] router partials
    const int tid = threadIdx.x;
    const int wave = tid >> 6, lane = tid & 63;
    const int col = lane & 15, quad = lane >> 4;
    const int b = blockIdx.y;
    const int s0 = blockIdx.x * 32;

    // ---- router partial: y[k] = dot(pool[b], Wr[:,k]) (per-block, redundant
    //      across blocks of same b; ~15KB L2 reads, hidden under staging) ----
    {
        int k = tid & 3, dbase = tid >> 2;     // thread covers d = dbase+64j
        float s = 0.f;
#pragma unroll
        for (int j = 0; j < 12; ++j) {
            int d = dbase + 64 * j;
            s += pool[b * DIMD + d] * Wr[d * KADP + k];
        }
        s += __shfl_xor(s, 4); s += __shfl_xor(s, 8);
        s += __shfl_xor(s, 16); s += __shfl_xor(s, 32);
        if (lane < 4) wsh[wave * 4 + lane] = s;   // lane==k for lanes 0..3
    }

    // ---- Phase 1: h[32 x 48] (this wave's kr quarter), k-split staging ----
    const float* xb = x + ((size_t)(b * NS + s0)) * DIMD;
    floatx4 acc[2][3];
#pragma unroll
    for (int mt = 0; mt < 2; ++mt)
#pragma unroll
        for (int j = 0; j < 3; ++j) acc[mt][j] = (floatx4){0.f, 0.f, 0.f, 0.f};

    const short* xl0 = smem + col * XSTR;
    const short* xl1 = smem + (16 + col) * XSTR;
    const int ntb = wave * 3;

    for (int h = 0; h < 2; ++h) {
        if (h) __syncthreads();                // all reads of half h-1 done
        // stage x half h: [32 rows x 384 floats] -> bf16 LDS
#pragma unroll 6
        for (int i = tid; i < 3072; i += 256) {   // 3072 float4
            int row = i / 96, c = i % 96;
            float4 v = *(const float4*)(xb + (size_t)row * DIMD + h * 384 + c * 4);
            short4v sv;
            sv[0] = f2bf(v.x); sv[1] = f2bf(v.y); sv[2] = f2bf(v.z); sv[3] = f2bf(v.w);
            *(short4v*)(smem + row * XSTR + c * 4) = sv;
        }
        __syncthreads();
        for (int kc = 0; kc < 12; ++kc) {
            short8 a0 = *(const short8*)(xl0 + kc * 32 + quad * 8);
            short8 a1 = *(const short8*)(xl1 + kc * 32 + quad * 8);
            int kcg = h * 12 + kc;
#pragma unroll
            for (int j = 0; j < 3; ++j) {
                short8 bf = *(const short8*)(WdP + ((size_t)((ntb + j) * 24 + kcg) * 64 + lane) * 8);
                acc[0][j] = __builtin_amdgcn_mfma_f32_16x16x32_bf16(a0, bf, acc[0][j], 0, 0, 0);
                acc[1][j] = __builtin_amdgcn_mfma_f32_16x16x32_bf16(a1, bf, acc[1][j], 0, 0, 0);
            }
        }
    }
    __syncthreads();    // all x_lds reads done before g overwrites the region

    // ---- router finish: softmax over 4 slots (redundant per thread) ----
    float y0 = (wsh[0] + wsh[4] + wsh[8] + wsh[12]) * (1.0f / NS) + br[0];
    float y1 = (wsh[1] + wsh[5] + wsh[9] + wsh[13]) * (1.0f / NS) + br[1];
    float y2 = (wsh[2] + wsh[6] + wsh[10] + wsh[14]) * (1.0f / NS) + br[2];
    float y3 = (wsh[3] + wsh[7] + wsh[11] + wsh[15]) * (1.0f / NS) + br[3];
    float mx = fmaxf(fmaxf(y0, y1), fmaxf(y2, y3));
    float e0 = __expf(y0 - mx), e1 = __expf(y1 - mx);
    float e2 = __expf(y2 - mx), e3 = __expf(y3 - mx);
    float inv = 1.0f / (e0 + e1 + e2 + e3);
    float w0 = e0 * inv, w1 = e1 * inv, w2 = e2 * inv, w3 = e3 * inv;

    // ---- epilogue: +bd, tanh-GELU, *w_k, bf16 -> g region (C -> A layout) ----
#pragma unroll
    for (int mt = 0; mt < 2; ++mt) {
#pragma unroll
        for (int j = 0; j < 3; ++j) {
            int kr = (ntb + j) * 16 + col;
            float bdv = bd[kr];
            int k = kr / RNK;
            float wk = (k == 0) ? w0 : (k == 1) ? w1 : (k == 2) ? w2 : w3;
#pragma unroll
            for (int reg = 0; reg < 4; ++reg) {
                float hh = acc[mt][j][reg] + bdv;
                float zz = 0.7978845608028654f * (hh + 0.044715f * hh * hh * hh);
                float e = __expf(2.0f * zz);
                float th = 1.0f - 2.0f / (e + 1.0f);      // tanh(zz)
                float g = 0.5f * hh * (1.0f + th) * wk;
                int row = mt * 16 + quad * 4 + reg;
                smem[row * GSTR + kr] = f2bf(g);
            }
        }
    }
    __syncthreads();

    // ---- Phase 2: out[32 x 192] (this wave's d quarter), two m-tile passes
    //      (ga[6]=24 VGPR per pass; WuP frags re-read from L2, cheap) ----
    float* outw = out + ((size_t)(b * NS + s0)) * DIMD;
    const int ntb2 = wave * 12;
#pragma unroll 1
    for (int mt = 0; mt < 2; ++mt) {
        short8 ga[6];
#pragma unroll
        for (int kc = 0; kc < 6; ++kc)
            ga[kc] = *(const short8*)(smem + (mt * 16 + col) * GSTR + kc * 32 + quad * 8);
        for (int p = 0; p < 6; ++p) {
            int nt = ntb2 + p * 2;
            floatx4 c0 = (floatx4){0.f, 0.f, 0.f, 0.f};
            floatx4 c1 = (floatx4){0.f, 0.f, 0.f, 0.f};
#pragma unroll
            for (int kc = 0; kc < 6; ++kc) {
                short8 b0 = *(const short8*)(WuP + ((size_t)((nt + 0) * 6 + kc) * 64 + lane) * 8);
                short8 b1 = *(const short8*)(WuP + ((size_t)((nt + 1) * 6 + kc) * 64 + lane) * 8);
                c0 = __builtin_amdgcn_mfma_f32_16x16x32_bf16(ga[kc], b0, c0, 0, 0, 0);
                c1 = __builtin_amdgcn_mfma_f32_16x16x32_bf16(ga[kc], b1, c1, 0, 0, 0);
            }
            int d0 = (nt + 0) * 16 + col, d1 = (nt + 1) * 16 + col;
            float bb0 = w0 * bu[0 * DIMD + d0] + w1 * bu[1 * DIMD + d0]
                      + w2 * bu[2 * DIMD + d0] + w3 * bu[3 * DIMD + d0];
            float bb1 = w0 * bu[0 * DIMD + d1] + w1 * bu[1 * DIMD + d1]
                      + w2 * bu[2 * DIMD + d1] + w3 * bu[3 * DIMD + d1];
#pragma unroll
            for (int reg = 0; reg < 4; ++reg) {
                int r0 = mt * 16 + quad * 4 + reg;
                __builtin_nontemporal_store(c0[reg] + bb0, &outw[(size_t)r0 * DIMD + d0]);
                __builtin_nontemporal_store(c1[reg] + bb1, &outw[(size_t)r0 * DIMD + d1]);
            }
        }
    }
}

// ---------------------------------------------------------------------------
extern "C" void kernel_launch(void* const* d_in, const int* in_sizes, int n_in,
                              void* d_out, int out_size, void* d_ws, size_t ws_size,
                              hipStream_t stream) {
    const float* x  = (const float*)d_in[0];
    const float* Wd = (const float*)d_in[1];
    const float* bd = (const float*)d_in[2];
    const float* Wu = (const float*)d_in[3];
    const float* bu = (const float*)d_in[4];
    const float* Wr = (const float*)d_in[5];
    const float* br = (const float*)d_in[6];
    float* out = (float*)d_out;

    char* ws = (char*)d_ws;
    float* pool = (float*)(ws);                // 6144 f32 = 24576 B
    short* WdP  = (short*)(ws + 24576);        // 147456 bf16 = 294912 B
    short* WuP  = (short*)(ws + 319488);       // 147456 bf16 = 294912 B (total 614400)

    hipMemsetAsync(pool, 0, NB * DIMD * sizeof(float), stream);
    prologue<<<1168, 256, 0, stream>>>(x, Wd, Wu, WdP, WuP, pool);
    adapter_main<<<dim3(128, 8), 256, 0, stream>>>(x, bd, WdP, WuP, pool, Wr, br, bu, out);
}